// Round 6
// baseline (232.852 us; speedup 1.0000x reference)
//
#include <hip/hip_runtime.h>
#include <hip/hip_bf16.h>
#include <math.h>

#define B 32
#define KLEN 2000
#define KDIM 512
#define QDIM 512
#define ADIM 512
#define VDIM 512
#define CONV_CH 10
#define CONV_K 201

#define KEXT 528                 // 512 key + 10 conv + 1 bias-one + 5 zero pad
#define NKS  33                  // KEXT / 16
#define CT_N 16                  // 512 / 32 col-tiles
#define TILE_BYTES (NKS * 1024)  // 33 ks x 64 lanes x 16B = 33792
#define SCR_BYTES  16384         // 2 regions x 4 rg x 4 pairs x 64 lanes x 8B

typedef __attribute__((ext_vector_type(8)))  short bf16x8;
typedef __attribute__((ext_vector_type(16))) float f32x16;
typedef __attribute__((ext_vector_type(4)))  float f32x4;
typedef __attribute__((ext_vector_type(2)))  float f32x2;

typedef const __attribute__((address_space(1))) unsigned int gu32;
typedef __attribute__((address_space(3))) unsigned int lu32;

__device__ __forceinline__ ushort f32_to_bf16(float f) {
    union { float f; unsigned int u; } v; v.f = f;
    unsigned int x = v.u;
    unsigned int r = (x + 0x7FFFu + ((x >> 16) & 1u)) >> 16;
    return (ushort)r;
}

__device__ __forceinline__ float fast_tanh(float x) {
    // tanh(x) = 1 - 2/(e^(2x)+1); stable at both extremes
    return 1.0f - 2.0f / (__expf(2.0f * x) + 1.0f);
}

// ---- K0: pack W_ext = [Wk | Wconv | bk | 0pad] into MFMA-B lane layout ----
// layout: [ct(16)][ks(33)][lane(64)][8 bf16]; lane = h*32+r;
// holds B[k = ks*16 + h*8 + jj][col = ct*32 + r]  (conflict-free ds_read at lane*16)
__global__ void k_pack_w(const float* __restrict__ Wk, const float* __restrict__ Wconv,
                         const float* __restrict__ bk, ushort* __restrict__ wp) {
    int t = blockIdx.x * 256 + threadIdx.x;        // 33792 16B-chunks
    int lane = t & 63;
    int idx = t >> 6;
    int ks = idx % NKS, ct = idx / NKS;
    int h = lane >> 5, r = lane & 31;
    int a = ct * 32 + r;
    int j0 = ks * 16 + h * 8;
    union { uint4 v; ushort u[8]; } pk;
    #pragma unroll
    for (int jj = 0; jj < 8; jj++) {
        int j = j0 + jj;
        float val;
        if (j < 512)       val = Wk[a * KDIM + j];
        else if (j < 522)  val = Wconv[a * CONV_CH + (j - 512)];
        else if (j == 522) val = bk[a];
        else               val = 0.f;
        pk.u[jj] = f32_to_bf16(val);
    }
    *(uint4*)(wp + (size_t)t * 8) = pk.v;
}

// ---- K1: qproj[b][a] = dot(query[b], Wq[a]) -----------------------------
__global__ void k_qproj(const float* __restrict__ query, const float* __restrict__ Wq,
                        float* __restrict__ qproj) {
    int t = blockIdx.x * 256 + threadIdx.x;        // 16384
    int b = t >> 9, a = t & 511;
    const f32x4* q = (const f32x4*)(query + b * QDIM);
    const f32x4* w = (const f32x4*)(Wq + a * QDIM);
    float acc = 0.f;
    #pragma unroll 4
    for (int i = 0; i < 128; i++) {
        f32x4 qv = q[i], wv = w[i];
        acc += qv[0]*wv[0] + qv[1]*wv[1] + qv[2]*wv[2] + qv[3]*wv[3];
    }
    qproj[t] = acc;
}

// ---- K2: conv_feat[b][c][k] = SAME cross-correlation --------------------
__global__ void k_conv(const float* __restrict__ aw_prev, const float* __restrict__ conv_w,
                       float* __restrict__ cf) {
    int t = blockIdx.x * 256 + threadIdx.x;
    if (t >= B * CONV_CH * KLEN) return;
    int k = t % KLEN;
    int c = (t / KLEN) % CONV_CH;
    int b = t / (KLEN * CONV_CH);
    const float* aw = aw_prev + b * KLEN;
    const float* w  = conv_w + c * CONV_K;
    int lo = k - 100;
    int t0 = lo < 0 ? -lo : 0;
    int t1 = (lo + CONV_K > KLEN) ? (KLEN - lo) : CONV_K;
    float acc = 0.f;
    for (int tt = t0; tt < t1; tt++) acc += w[tt] * aw[lo + tt];
    cf[t] = acc;
}

// ---- K3: fused kproj-ext GEMM + additive score --------------------------
// 512 threads = 8 waves = 4 row-groups x 2 K-groups. kg0: ks 0..16, kg1: ks 17..32.
// Partners exchange pre-tanh partial accs via LDS scratch once per col-tile.
__global__ __launch_bounds__(512, 4)
void k_main(const float* __restrict__ key, const ushort* __restrict__ wp,
            const float* __restrict__ qproj, const float* __restrict__ cf,
            const float* __restrict__ vvec, const int* __restrict__ mask,
            float* __restrict__ e_out) {
    __shared__ char smem[TILE_BYTES + SCR_BYTES];  // 49.2 KB: B tile + combine scratch
    const int tid  = threadIdx.x;
    const int wave = tid >> 6, lane = tid & 63;
    const int rg = wave >> 1, kg = wave & 1;
    const int r = lane & 31, h = lane >> 5;
    const int wrow0 = blockIdx.x * 128 + rg * 32;
    const int wbase = wrow0 + 4 * h;               // C/D row base for pats

    // stage one col-tile of B into LDS (async, no VGPR round-trip)
    auto stage = [&](int ct) {
        const char* src = (const char*)wp + (size_t)ct * TILE_BYTES + lane * 16;
        for (int ks = wave; ks < NKS; ks += 8) {
            __builtin_amdgcn_global_load_lds((gu32*)(src + ks * 1024),
                                             (lu32*)(smem + ks * 1024), 16, 0, 0);
        }
    };
    stage(0);   // overlaps with the A-fragment loads below

    // ---- A fragments: 17 frags (kg0: ks 0..16) or 16 frags (kg1: ks 17..32)
    bf16x8 A[17];
    {
        const int grow = wrow0 + r;
        const float* kp = key + (size_t)grow * KDIM + h * 8;
        if (kg == 0) {
            #pragma unroll
            for (int i = 0; i < 17; i++) {
                f32x4 f0 = __builtin_nontemporal_load((const f32x4*)(kp + i * 16));
                f32x4 f1 = __builtin_nontemporal_load((const f32x4*)(kp + i * 16 + 4));
                union { bf16x8 v8; ushort u[8]; } pk;
                pk.u[0] = f32_to_bf16(f0[0]); pk.u[1] = f32_to_bf16(f0[1]);
                pk.u[2] = f32_to_bf16(f0[2]); pk.u[3] = f32_to_bf16(f0[3]);
                pk.u[4] = f32_to_bf16(f1[0]); pk.u[5] = f32_to_bf16(f1[1]);
                pk.u[6] = f32_to_bf16(f1[2]); pk.u[7] = f32_to_bf16(f1[3]);
                A[i] = pk.v8;
            }
        } else {
            #pragma unroll
            for (int i = 0; i < 15; i++) {        // ks = 17+i -> cols 272..511
                f32x4 f0 = __builtin_nontemporal_load((const f32x4*)(kp + (17 + i) * 16));
                f32x4 f1 = __builtin_nontemporal_load((const f32x4*)(kp + (17 + i) * 16 + 4));
                union { bf16x8 v8; ushort u[8]; } pk;
                pk.u[0] = f32_to_bf16(f0[0]); pk.u[1] = f32_to_bf16(f0[1]);
                pk.u[2] = f32_to_bf16(f0[2]); pk.u[3] = f32_to_bf16(f0[3]);
                pk.u[4] = f32_to_bf16(f1[0]); pk.u[5] = f32_to_bf16(f1[1]);
                pk.u[6] = f32_to_bf16(f1[2]); pk.u[7] = f32_to_bf16(f1[3]);
                A[i] = pk.v8;
            }
            // ks=32: j = 512 + h*8 + jj -> cf[0..9], 1.0, zeros
            int b_a = grow / KLEN, kpos = grow % KLEN;
            const float* cfb = cf + ((size_t)b_a * CONV_CH) * KLEN + kpos;
            union { bf16x8 v8; ushort u[8]; } pk;
            if (h == 0) {
                #pragma unroll
                for (int jj = 0; jj < 8; jj++) pk.u[jj] = f32_to_bf16(cfb[(size_t)jj * KLEN]);
            } else {
                pk.u[0] = f32_to_bf16(cfb[(size_t)8 * KLEN]);
                pk.u[1] = f32_to_bf16(cfb[(size_t)9 * KLEN]);
                pk.u[2] = 0x3F80;  // 1.0f bf16
                pk.u[3] = 0; pk.u[4] = 0; pk.u[5] = 0; pk.u[6] = 0; pk.u[7] = 0;
            }
            A[15] = pk.v8;
        }
    }
    __syncthreads();   // B tile 0 staged (vmcnt drained) + all waves ready

    float pe[8];
    #pragma unroll
    for (int j = 0; j < 8; j++) pe[j] = 0.f;

    float* scr = (float*)(smem + TILE_BYTES);
    const char* sbl = smem + lane * 16;

    for (int ct = 0; ct < CT_N; ct++) {
        // ---- MFMA over this wave's K-half ------------------------------
        f32x16 acc = {0,0,0,0,0,0,0,0,0,0,0,0,0,0,0,0};
        if (kg == 0) {
            #pragma unroll
            for (int i = 0; i < 17; i++) {
                bf16x8 bfrag = *(const bf16x8*)(sbl + i * 1024);
                acc = __builtin_amdgcn_mfma_f32_32x32x16_bf16(A[i], bfrag, acc, 0, 0, 0);
            }
        } else {
            #pragma unroll
            for (int i = 0; i < 16; i++) {
                bf16x8 bfrag = *(const bf16x8*)(sbl + (17 + i) * 1024);
                acc = __builtin_amdgcn_mfma_f32_32x32x16_bf16(A[i], bfrag, acc, 0, 0, 0);
            }
        }
        __syncthreads();   // bar1: all B(ct) reads done; scratch free

        // ---- exchange: kg0 sends acc[8..15] (region0), kg1 sends acc[0..7] (region1)
        {
            f32x2* w = (f32x2*)scr + (kg == 0 ? 0 : 1024) + rg * 256 + lane;
            if (kg == 0) {
                #pragma unroll
                for (int p = 0; p < 4; p++) { f32x2 t; t[0] = acc[8+2*p]; t[1] = acc[9+2*p]; w[p*64] = t; }
            } else {
                #pragma unroll
                for (int p = 0; p < 4; p++) { f32x2 t; t[0] = acc[2*p];   t[1] = acc[1+2*p]; w[p*64] = t; }
            }
        }
        __syncthreads();   // bar2: scratch visible

        // issue next B tile now; its latency hides under the epilogue VALU
        if (ct + 1 < CT_N) stage(ct + 1);

        // ---- combine + epilogue on my half of the rows -----------------
        float av[8];
        {
            f32x2* rd = (f32x2*)scr + (kg == 0 ? 1024 : 0) + rg * 256 + lane;
            f32x2 t0 = rd[0], t1 = rd[64], t2 = rd[128], t3 = rd[192];
            if (kg == 0) {
                av[0] = acc[0] + t0[0]; av[1] = acc[1] + t0[1];
                av[2] = acc[2] + t1[0]; av[3] = acc[3] + t1[1];
                av[4] = acc[4] + t2[0]; av[5] = acc[5] + t2[1];
                av[6] = acc[6] + t3[0]; av[7] = acc[7] + t3[1];
            } else {
                av[0] = acc[8]  + t0[0]; av[1] = acc[9]  + t0[1];
                av[2] = acc[10] + t1[0]; av[3] = acc[11] + t1[1];
                av[4] = acc[12] + t2[0]; av[5] = acc[13] + t2[1];
                av[6] = acc[14] + t3[0]; av[7] = acc[15] + t3[1];
            }
        }
        const int col = ct * 32 + r;
        const float va = vvec[col];
        const int patbase = kg << 4;
        #pragma unroll
        for (int j = 0; j < 8; j++) {
            const int pat = patbase + (j & 3) + 8 * (j >> 2);
            int row = wbase + pat;
            int bb = row / KLEN;
            float x = av[j] + qproj[bb * ADIM + col];
            pe[j] += fast_tanh(x) * va;
        }
        __syncthreads();   // bar3: vmcnt drained -> B(ct+1) ready; scratch reads done
    }

    // reduce over the 32 lanes (cols) sharing the same row set
    #pragma unroll
    for (int j = 0; j < 8; j++) {
        float s = pe[j];
        s += __shfl_xor(s, 1);
        s += __shfl_xor(s, 2);
        s += __shfl_xor(s, 4);
        s += __shfl_xor(s, 8);
        s += __shfl_xor(s, 16);
        pe[j] = s;
    }
    if (r == 0) {
        const int patbase = kg << 4;
        #pragma unroll
        for (int j = 0; j < 8; j++) {
            const int pat = patbase + (j & 3) + 8 * (j >> 2);
            int row = wbase + pat;
            e_out[row] = mask[row] ? pe[j] : -3.4028235e38f;
        }
    }
}

// ---- K4: row softmax -> aw ----------------------------------------------
__global__ void k_softmax(const float* __restrict__ e, float* __restrict__ aw) {
    int b = blockIdx.x;
    const float* er = e + b * KLEN;
    __shared__ float redm[4], reds[4];
    int tid = threadIdx.x, lane = tid & 63, wv = tid >> 6;
    float m = -3.4028235e38f;
    for (int k = tid; k < KLEN; k += 256) m = fmaxf(m, er[k]);
    for (int o = 32; o; o >>= 1) m = fmaxf(m, __shfl_xor(m, o));
    if (lane == 0) redm[wv] = m;
    __syncthreads();
    m = fmaxf(fmaxf(redm[0], redm[1]), fmaxf(redm[2], redm[3]));
    float s = 0.f;
    for (int k = tid; k < KLEN; k += 256) s += __expf(er[k] - m);
    for (int o = 32; o; o >>= 1) s += __shfl_xor(s, o);
    if (lane == 0) reds[wv] = s;
    __syncthreads();
    s = reds[0] + reds[1] + reds[2] + reds[3];
    float inv = 1.0f / s;
    for (int k = tid; k < KLEN; k += 256) aw[b * KLEN + k] = __expf(er[k] - m) * inv;
}

// ---- K5a: partial cv over 16 k-chunks of 125 ----------------------------
__global__ void k_cvpart(const float* __restrict__ aw, const float* __restrict__ value,
                         float* __restrict__ part) {
    int b = blockIdx.x >> 4, chunk = blockIdx.x & 15;
    int k0 = chunk * 125;
    __shared__ float sa[125];
    int tid = threadIdx.x;
    if (tid < 125) sa[tid] = aw[b * KLEN + k0 + tid];
    __syncthreads();
    const float* vp = value + ((size_t)b * KLEN + k0) * VDIM + tid * 2;
    float ax = 0.f, ay = 0.f;
    #pragma unroll 5
    for (int k = 0; k < 125; k++) {
        const f32x2 vv = __builtin_nontemporal_load((const f32x2*)(vp + (size_t)k * VDIM));
        ax += sa[k] * vv[0]; ay += sa[k] * vv[1];
    }
    f32x2 o; o[0] = ax; o[1] = ay;
    *(f32x2*)(part + ((b * 16 + chunk) * VDIM) + tid * 2) = o;
}

// ---- K5b: reduce partials -> cv -----------------------------------------
__global__ void k_cvreduce(const float* __restrict__ part, float* __restrict__ cv) {
    int t = blockIdx.x * 256 + threadIdx.x;  // 16384
    int b = t >> 9, col = t & 511;
    float s = 0.f;
    #pragma unroll
    for (int c = 0; c < 16; c++) s += part[(b * 16 + c) * VDIM + col];
    cv[t] = s;
}

extern "C" void kernel_launch(void* const* d_in, const int* in_sizes, int n_in,
                              void* d_out, int out_size, void* d_ws, size_t ws_size,
                              hipStream_t stream) {
    const float* key     = (const float*)d_in[0];
    const float* value   = (const float*)d_in[1];
    const float* query   = (const float*)d_in[2];
    const float* aw_prev = (const float*)d_in[3];
    const int*   mask    = (const int*)d_in[4];
    const float* Wk      = (const float*)d_in[5];
    const float* bk      = (const float*)d_in[6];
    const float* Wq      = (const float*)d_in[7];
    const float* conv_w  = (const float*)d_in[8];
    const float* Wconv   = (const float*)d_in[9];
    const float* vvec    = (const float*)d_in[10];

    char* ws = (char*)d_ws;
    ushort* wp   = (ushort*)(ws + 0);          // 16*33*64*8*2 = 540672
    float* qproj = (float*)(ws + 540672);      // 32*512*4     = 65536
    float* cf    = (float*)(ws + 606208);      // 32*10*2000*4 = 2560000
    float* e     = (float*)(ws + 3166208);     // 32*2000*4    = 256000
    float* part  = (float*)(ws + 3422208);     // 32*16*512*4  = 1048576

    float* cv = (float*)d_out;                 // [32][512]
    float* aw = (float*)d_out + B * VDIM;      // [32][2000]

    k_pack_w  <<<132,  256, 0, stream>>>(Wk, Wconv, bk, wp);
    k_qproj   <<<64,   256, 0, stream>>>(query, Wq, qproj);
    k_conv    <<<2500, 256, 0, stream>>>(aw_prev, conv_w, cf);
    k_main    <<<500,  512, 0, stream>>>(key, wp, qproj, cf, vvec, mask, e);
    k_softmax <<<B,    256, 0, stream>>>(e, aw);
    k_cvpart  <<<B*16, 256, 0, stream>>>(aw, value, part);
    k_cvreduce<<<64,   256, 0, stream>>>(part, cv);
}

// Round 7
// 164.187 us; speedup vs baseline: 1.4182x; 1.4182x over previous
//
#include <hip/hip_runtime.h>
#include <hip/hip_bf16.h>
#include <math.h>

#define B 32
#define KLEN 2000
#define KDIM 512
#define QDIM 512
#define ADIM 512
#define VDIM 512
#define CONV_CH 10
#define CONV_K 201
#define NROWS (B*KLEN)

#define NKS  33                  // 528 / 16 (512 key + 10 conv + 1 bias + 5 pad)
#define ZERO16 {0,0,0,0,0,0,0,0,0,0,0,0,0,0,0,0}

typedef __attribute__((ext_vector_type(8)))  short bf16x8;
typedef __attribute__((ext_vector_type(16))) float f32x16;
typedef __attribute__((ext_vector_type(4)))  float f32x4;
typedef __attribute__((ext_vector_type(2)))  float f32x2;

__device__ __forceinline__ ushort f32_to_bf16(float f) {
    union { float f; unsigned int u; } v; v.f = f;
    unsigned int x = v.u;
    unsigned int r = (x + 0x7FFFu + ((x >> 16) & 1u)) >> 16;
    return (ushort)r;
}

__device__ __forceinline__ float fast_tanh(float x) {
    // tanh(x) = 1 - 2/(e^(2x)+1); stable at both extremes
    return 1.0f - 2.0f / (__expf(2.0f * x) + 1.0f);
}

#define MFMA32(a, bfr, c) __builtin_amdgcn_mfma_f32_32x32x16_bf16(a, bfr, c, 0, 0, 0)

// ---- K0: pack W_ext = [Wk | Wconv | bk | 0pad] into MFMA-B lane layout ----
// layout: [nt(16)][ks(33)][lane(64)][8 bf16]; lane = h*32+r;
// holds B[k = ks*16 + h*8 + jj][col = nt*32 + r]
__global__ void k_pack_w(const float* __restrict__ Wk, const float* __restrict__ Wconv,
                         const float* __restrict__ bk, ushort* __restrict__ wp) {
    int t = blockIdx.x * 256 + threadIdx.x;        // 33792 16B-chunks
    int lane = t & 63;
    int idx = t >> 6;
    int ks = idx % NKS, nt = idx / NKS;
    int h = lane >> 5, r = lane & 31;
    int a = nt * 32 + r;
    int j0 = ks * 16 + h * 8;
    union { uint4 v; ushort u[8]; } pk;
    #pragma unroll
    for (int jj = 0; jj < 8; jj++) {
        int j = j0 + jj;
        float val;
        if (j < 512)       val = Wk[a * KDIM + j];
        else if (j < 522)  val = Wconv[a * CONV_CH + (j - 512)];
        else if (j == 522) val = bk[a];
        else               val = 0.f;
        pk.u[jj] = f32_to_bf16(val);
    }
    *(uint4*)(wp + (size_t)t * 8) = pk.v;
}

// ---- K1: qproj[b][a] = dot(query[b], Wq[a]) -----------------------------
__global__ void k_qproj(const float* __restrict__ query, const float* __restrict__ Wq,
                        float* __restrict__ qproj) {
    int t = blockIdx.x * 256 + threadIdx.x;        // 16384
    int b = t >> 9, a = t & 511;
    const f32x4* q = (const f32x4*)(query + b * QDIM);
    const f32x4* w = (const f32x4*)(Wq + a * QDIM);
    float acc = 0.f;
    #pragma unroll 4
    for (int i = 0; i < 128; i++) {
        f32x4 qv = q[i], wv = w[i];
        acc += qv[0]*wv[0] + qv[1]*wv[1] + qv[2]*wv[2] + qv[3]*wv[3];
    }
    qproj[t] = acc;
}

// ---- K2: conv_feat[b][c][k] = SAME cross-correlation --------------------
__global__ void k_conv(const float* __restrict__ aw_prev, const float* __restrict__ conv_w,
                       float* __restrict__ cf) {
    int t = blockIdx.x * 256 + threadIdx.x;
    if (t >= B * CONV_CH * KLEN) return;
    int k = t % KLEN;
    int c = (t / KLEN) % CONV_CH;
    int b = t / (KLEN * CONV_CH);
    const float* aw = aw_prev + b * KLEN;
    const float* w  = conv_w + c * CONV_K;
    int lo = k - 100;
    int t0 = lo < 0 ? -lo : 0;
    int t1 = (lo + CONV_K > KLEN) ? (KLEN - lo) : CONV_K;
    float acc = 0.f;
    for (int tt = t0; tt < t1; tt++) acc += w[tt] * aw[lo + tt];
    cf[t] = acc;
}

// ---- K3: fused kproj-ext GEMM + additive score --------------------------
// Block: 256 thr = 4 waves; each wave = 64 rows x 128 cols (2m x 4n MFMA block).
// A (key bf16, swizzled) in 64KB LDS staged once; B read from L2; no loop barriers.
// Writes per-colgroup partials ep[wc][row]; mask+sum folded into softmax.
__global__ __launch_bounds__(256, 2)
void k_main(const float* __restrict__ key, const ushort* __restrict__ wp,
            const float* __restrict__ qproj, const float* __restrict__ cf,
            const float* __restrict__ vvec, float* __restrict__ ep) {
    __shared__ char Alds[65536];                   // 64 rows x 512 bf16, swizzled
    const int tid = threadIdx.x;
    const int wc = tid >> 6, lane = tid & 63;
    const int r = lane & 31, h = lane >> 5;
    const int row0 = blockIdx.x * 64;

    // ---- A_cf fragments: conv features + bias-one (rows r, 32+r) -------
    auto build_cf = [&](int row) -> bf16x8 {
        int b = row / KLEN, kpos = row % KLEN;
        const float* cfb = cf + ((size_t)b * CONV_CH) * KLEN + kpos;
        union { bf16x8 v8; ushort u[8]; } pk;
        if (h == 0) {
            #pragma unroll
            for (int jj = 0; jj < 8; jj++) pk.u[jj] = f32_to_bf16(cfb[(size_t)jj * KLEN]);
        } else {
            pk.u[0] = f32_to_bf16(cfb[(size_t)8 * KLEN]);
            pk.u[1] = f32_to_bf16(cfb[(size_t)9 * KLEN]);
            pk.u[2] = 0x3F80;  // 1.0f bf16 (bias column)
            pk.u[3] = 0; pk.u[4] = 0; pk.u[5] = 0; pk.u[6] = 0; pk.u[7] = 0;
        }
        return pk.v8;
    };
    bf16x8 Acf0 = build_cf(row0 + r);
    bf16x8 Acf1 = build_cf(row0 + 32 + r);

    // ---- stage key f32 -> bf16 into swizzled LDS ------------------------
    // chunk ch: row=ch>>6, cx=ch&63 covers bytes [cx*16,+16) of row.
    // swizzle: byte_off ^= (row&31)<<4  (read side uses same XOR -> <=2-way)
    #pragma unroll
    for (int i = 0; i < 16; i++) {
        int ch = tid + i * 256;
        int arow = ch >> 6, cx = ch & 63;
        const float* kp = key + (size_t)(row0 + arow) * KDIM + cx * 8;
        f32x4 f0 = __builtin_nontemporal_load((const f32x4*)kp);
        f32x4 f1 = __builtin_nontemporal_load((const f32x4*)(kp + 4));
        union { uint4 v; ushort u[8]; } pk;
        pk.u[0] = f32_to_bf16(f0[0]); pk.u[1] = f32_to_bf16(f0[1]);
        pk.u[2] = f32_to_bf16(f0[2]); pk.u[3] = f32_to_bf16(f0[3]);
        pk.u[4] = f32_to_bf16(f1[0]); pk.u[5] = f32_to_bf16(f1[1]);
        pk.u[6] = f32_to_bf16(f1[2]); pk.u[7] = f32_to_bf16(f1[3]);
        int off = arow * 1024 + cx * 16;
        off ^= (arow & 31) << 4;
        *(uint4*)(Alds + off) = pk.v;
    }
    __syncthreads();   // the only barrier

    // ---- main loop: K=512 from LDS, B fragments from L2 -----------------
    const ushort* bp0 = wp + ((size_t)(wc * 4 + 0) * NKS * 64 + lane) * 8;
    const ushort* bp1 = wp + ((size_t)(wc * 4 + 1) * NKS * 64 + lane) * 8;
    const ushort* bp2 = wp + ((size_t)(wc * 4 + 2) * NKS * 64 + lane) * 8;
    const ushort* bp3 = wp + ((size_t)(wc * 4 + 3) * NKS * 64 + lane) * 8;
    const int abase0 = r * 1024 + h * 16;
    const int abase1 = abase0 + 32768;
    const int swz = r << 4;

    f32x16 c00 = ZERO16, c01 = ZERO16, c02 = ZERO16, c03 = ZERO16;
    f32x16 c10 = ZERO16, c11 = ZERO16, c12 = ZERO16, c13 = ZERO16;

    #pragma unroll 2
    for (int ks = 0; ks < 32; ks++) {
        bf16x8 a0 = *(const bf16x8*)(Alds + ((abase0 + ks * 32) ^ swz));
        bf16x8 a1 = *(const bf16x8*)(Alds + ((abase1 + ks * 32) ^ swz));
        bf16x8 b0 = *(const bf16x8*)(bp0 + ks * 512);
        bf16x8 b1 = *(const bf16x8*)(bp1 + ks * 512);
        bf16x8 b2 = *(const bf16x8*)(bp2 + ks * 512);
        bf16x8 b3 = *(const bf16x8*)(bp3 + ks * 512);
        c00 = MFMA32(a0, b0, c00); c01 = MFMA32(a0, b1, c01);
        c02 = MFMA32(a0, b2, c02); c03 = MFMA32(a0, b3, c03);
        c10 = MFMA32(a1, b0, c10); c11 = MFMA32(a1, b1, c11);
        c12 = MFMA32(a1, b2, c12); c13 = MFMA32(a1, b3, c13);
    }
    {   // ks = 32: conv features + bias via register A fragments
        bf16x8 b0 = *(const bf16x8*)(bp0 + 32 * 512);
        bf16x8 b1 = *(const bf16x8*)(bp1 + 32 * 512);
        bf16x8 b2 = *(const bf16x8*)(bp2 + 32 * 512);
        bf16x8 b3 = *(const bf16x8*)(bp3 + 32 * 512);
        c00 = MFMA32(Acf0, b0, c00); c01 = MFMA32(Acf0, b1, c01);
        c02 = MFMA32(Acf0, b2, c02); c03 = MFMA32(Acf0, b3, c03);
        c10 = MFMA32(Acf1, b0, c10); c11 = MFMA32(Acf1, b1, c11);
        c12 = MFMA32(Acf1, b2, c12); c13 = MFMA32(Acf1, b3, c13);
    }

    // ---- epilogue: + qproj, tanh, * v, per-lane partial sums ------------
    const int colb = wc * 128 + r;
    const float v0 = vvec[colb], v1 = vvec[colb + 32];
    const float v2 = vvec[colb + 64], v3 = vvec[colb + 96];
    const int blo = row0 / KLEN;
    const int bhi = (row0 + 63) / KLEN;
    const int split = (blo + 1) * KLEN;
    const float ql0 = qproj[blo * ADIM + colb],      qh0 = qproj[bhi * ADIM + colb];
    const float ql1 = qproj[blo * ADIM + colb + 32], qh1 = qproj[bhi * ADIM + colb + 32];
    const float ql2 = qproj[blo * ADIM + colb + 64], qh2 = qproj[bhi * ADIM + colb + 64];
    const float ql3 = qproj[blo * ADIM + colb + 96], qh3 = qproj[bhi * ADIM + colb + 96];

    float sm0[16], sm1[16];
    #pragma unroll
    for (int i = 0; i < 16; i++) {
        const int pat = (i & 3) + 8 * (i >> 2) + 4 * h;
        {
            bool hi = (row0 + pat) >= split;
            sm0[i] = fast_tanh(c00[i] + (hi ? qh0 : ql0)) * v0
                   + fast_tanh(c01[i] + (hi ? qh1 : ql1)) * v1
                   + fast_tanh(c02[i] + (hi ? qh2 : ql2)) * v2
                   + fast_tanh(c03[i] + (hi ? qh3 : ql3)) * v3;
        }
        {
            bool hi = (row0 + 32 + pat) >= split;
            sm1[i] = fast_tanh(c10[i] + (hi ? qh0 : ql0)) * v0
                   + fast_tanh(c11[i] + (hi ? qh1 : ql1)) * v1
                   + fast_tanh(c12[i] + (hi ? qh2 : ql2)) * v2
                   + fast_tanh(c13[i] + (hi ? qh3 : ql3)) * v3;
        }
    }

    // reduce across the 32 col-lanes (h halves hold different rows)
    #pragma unroll
    for (int i = 0; i < 16; i++) {
        float t0 = sm0[i], t1 = sm1[i];
        t0 += __shfl_xor(t0, 1);  t1 += __shfl_xor(t1, 1);
        t0 += __shfl_xor(t0, 2);  t1 += __shfl_xor(t1, 2);
        t0 += __shfl_xor(t0, 4);  t1 += __shfl_xor(t1, 4);
        t0 += __shfl_xor(t0, 8);  t1 += __shfl_xor(t1, 8);
        t0 += __shfl_xor(t0, 16); t1 += __shfl_xor(t1, 16);
        sm0[i] = t0; sm1[i] = t1;
    }
    if (r == 0) {
        float* epw = ep + (size_t)wc * NROWS;
        #pragma unroll
        for (int i = 0; i < 16; i++) {
            const int pat = (i & 3) + 8 * (i >> 2) + 4 * h;
            epw[row0 + pat]      = sm0[i];
            epw[row0 + 32 + pat] = sm1[i];
        }
    }
}

// ---- K4: row softmax over summed partials -> aw -------------------------
__global__ void k_softmax(const float* __restrict__ ep, const int* __restrict__ mask,
                          float* __restrict__ aw) {
    int b = blockIdx.x;
    __shared__ float se[KLEN];
    __shared__ float redm[4], reds[4];
    int tid = threadIdx.x, lane = tid & 63, wv = tid >> 6;
    for (int k = tid; k < KLEN; k += 256) {
        int idx = b * KLEN + k;
        float val = ep[idx] + ep[NROWS + idx] + ep[2 * NROWS + idx] + ep[3 * NROWS + idx];
        se[k] = mask[idx] ? val : -3.4028235e38f;
    }
    __syncthreads();
    float m = -3.4028235e38f;
    for (int k = tid; k < KLEN; k += 256) m = fmaxf(m, se[k]);
    for (int o = 32; o; o >>= 1) m = fmaxf(m, __shfl_xor(m, o));
    if (lane == 0) redm[wv] = m;
    __syncthreads();
    m = fmaxf(fmaxf(redm[0], redm[1]), fmaxf(redm[2], redm[3]));
    float s = 0.f;
    for (int k = tid; k < KLEN; k += 256) s += __expf(se[k] - m);
    for (int o = 32; o; o >>= 1) s += __shfl_xor(s, o);
    if (lane == 0) reds[wv] = s;
    __syncthreads();
    s = reds[0] + reds[1] + reds[2] + reds[3];
    float inv = 1.0f / s;
    for (int k = tid; k < KLEN; k += 256) aw[b * KLEN + k] = __expf(se[k] - m) * inv;
}

// ---- K5a: partial cv over 16 k-chunks of 125 ----------------------------
__global__ void k_cvpart(const float* __restrict__ aw, const float* __restrict__ value,
                         float* __restrict__ part) {
    int b = blockIdx.x >> 4, chunk = blockIdx.x & 15;
    int k0 = chunk * 125;
    __shared__ float sa[125];
    int tid = threadIdx.x;
    if (tid < 125) sa[tid] = aw[b * KLEN + k0 + tid];
    __syncthreads();
    const float* vp = value + ((size_t)b * KLEN + k0) * VDIM + tid * 2;
    float ax = 0.f, ay = 0.f;
    #pragma unroll 5
    for (int k = 0; k < 125; k++) {
        const f32x2 vv = __builtin_nontemporal_load((const f32x2*)(vp + (size_t)k * VDIM));
        ax += sa[k] * vv[0]; ay += sa[k] * vv[1];
    }
    f32x2 o; o[0] = ax; o[1] = ay;
    *(f32x2*)(part + ((b * 16 + chunk) * VDIM) + tid * 2) = o;
}

// ---- K5b: reduce partials -> cv -----------------------------------------
__global__ void k_cvreduce(const float* __restrict__ part, float* __restrict__ cv) {
    int t = blockIdx.x * 256 + threadIdx.x;  // 16384
    int b = t >> 9, col = t & 511;
    float s = 0.f;
    #pragma unroll
    for (int c = 0; c < 16; c++) s += part[(b * 16 + c) * VDIM + col];
    cv[t] = s;
}

extern "C" void kernel_launch(void* const* d_in, const int* in_sizes, int n_in,
                              void* d_out, int out_size, void* d_ws, size_t ws_size,
                              hipStream_t stream) {
    const float* key     = (const float*)d_in[0];
    const float* value   = (const float*)d_in[1];
    const float* query   = (const float*)d_in[2];
    const float* aw_prev = (const float*)d_in[3];
    const int*   mask    = (const int*)d_in[4];
    const float* Wk      = (const float*)d_in[5];
    const float* bk      = (const float*)d_in[6];
    const float* Wq      = (const float*)d_in[7];
    const float* conv_w  = (const float*)d_in[8];
    const float* Wconv   = (const float*)d_in[9];
    const float* vvec    = (const float*)d_in[10];

    char* ws = (char*)d_ws;
    ushort* wp   = (ushort*)(ws + 0);          // 16*33*64*8*2 = 540672
    float* qproj = (float*)(ws + 540672);      // 32*512*4     = 65536
    float* cf    = (float*)(ws + 606208);      // 32*10*2000*4 = 2560000
    float* ep    = (float*)(ws + 3166208);     // 4*64000*4    = 1024000
    float* part  = (float*)(ws + 0);           // 32*16*512*4 = 1048576 (wp/qproj/cf dead by then)

    float* cv = (float*)d_out;                 // [32][512]
    float* aw = (float*)d_out + B * VDIM;      // [32][2000]

    k_pack_w  <<<132,  256, 0, stream>>>(Wk, Wconv, bk, wp);
    k_qproj   <<<64,   256, 0, stream>>>(query, Wq, qproj);
    k_conv    <<<2500, 256, 0, stream>>>(aw_prev, conv_w, cf);
    k_main    <<<1000, 256, 0, stream>>>(key, wp, qproj, cf, vvec, ep);
    k_softmax <<<B,    256, 0, stream>>>(ep, mask, aw);
    k_cvpart  <<<B*16, 256, 0, stream>>>(aw, value, part);
    k_cvreduce<<<64,   256, 0, stream>>>(part, cv);
}